// Round 1
// baseline (439.787 us; speedup 1.0000x reference)
//
#include <hip/hip_runtime.h>
#include <math.h>

// Problem constants (B=8, S=4096, D=1024, E=64, Dq=256)
#define DIM   1024
#define NE    64
#define NQ    256
#define NCOL  320   // NE + NQ
#define BM    64    // tokens per block
#define BK    32    // K-chunk

// Thread layout: 256 threads = 16 row-groups (r) x 16 col-groups (c)
// Each thread: 4 tokens (r*4..r*4+3) x 20 cols (c*20..c*20+19)

__global__ __launch_bounds__(256)
void ur_fused(const float* __restrict__ hs,    // [M, 1024]
              const float* __restrict__ Wr,    // [64, 1024]
              const float* __restrict__ br,    // [64]
              const float* __restrict__ Wu1,   // [256, 1024]
              const float* __restrict__ bu1,   // [256]
              const float* __restrict__ Wu2,   // [256]  (shape [1,256])
              const float* __restrict__ bu2,   // [1]
              float* __restrict__ out,         // flat: w[4M] | idx[4M] | k[M]
              int M) {
  __shared__ float As[BK][BM];    // 8 KB, k-major
  __shared__ float Bs[BK][NCOL];  // 40 KB, k-major
  __shared__ float Lg[BM][NE];    // 16 KB router logits
  __shared__ float Xp[16][BM];    // 4 KB uncertainty partials
  __shared__ float Xs[BM];        // per-token pre-sigmoid

  const int tid = threadIdx.x;
  const int m0 = blockIdx.x * BM;
  const int r = tid >> 4;   // 0..15
  const int c = tid & 15;   // 0..15

  float acc[4][20];
#pragma unroll
  for (int j = 0; j < 4; ++j)
#pragma unroll
    for (int n = 0; n < 20; ++n) acc[j][n] = 0.f;

  for (int k0 = 0; k0 < DIM; k0 += BK) {
    // ---- stage A tile: 64 tokens x 32 k (512 float4, 2 per thread) ----
#pragma unroll
    for (int l = 0; l < 2; ++l) {
      int idx = tid + l * 256;      // 0..511
      int ta = idx >> 3;            // token 0..63
      int kq = idx & 7;             // float4 slot 0..7
      const float4 v = *reinterpret_cast<const float4*>(
          &hs[(size_t)(m0 + ta) * DIM + k0 + kq * 4]);
      As[kq * 4 + 0][ta] = v.x;
      As[kq * 4 + 1][ta] = v.y;
      As[kq * 4 + 2][ta] = v.z;
      As[kq * 4 + 3][ta] = v.w;
    }
    // ---- stage B tile: 320 rows x 32 k (2560 float4, 10 per thread) ----
#pragma unroll
    for (int l = 0; l < 10; ++l) {
      int idx = tid + l * 256;      // 0..2559
      int row = idx >> 3;           // 0..319
      int kq = idx & 7;
      const float* wsrc = (row < NE) ? (Wr + (size_t)row * DIM)
                                     : (Wu1 + (size_t)(row - NE) * DIM);
      const float4 v = *reinterpret_cast<const float4*>(&wsrc[k0 + kq * 4]);
      Bs[kq * 4 + 0][row] = v.x;
      Bs[kq * 4 + 1][row] = v.y;
      Bs[kq * 4 + 2][row] = v.z;
      Bs[kq * 4 + 3][row] = v.w;
    }
    __syncthreads();

    // ---- compute: 80 FMA per kk, aligned float4 LDS reads ----
#pragma unroll
    for (int kk = 0; kk < BK; ++kk) {
      const float4 av = *reinterpret_cast<const float4*>(&As[kk][r * 4]);
      float a[4] = {av.x, av.y, av.z, av.w};
#pragma unroll
      for (int g = 0; g < 5; ++g) {
        const float4 bv = *reinterpret_cast<const float4*>(&Bs[kk][c * 20 + g * 4]);
        float b[4] = {bv.x, bv.y, bv.z, bv.w};
#pragma unroll
        for (int q = 0; q < 4; ++q)
#pragma unroll
          for (int j = 0; j < 4; ++j)
            acc[j][g * 4 + q] = fmaf(a[j], b[q], acc[j][g * 4 + q]);
      }
    }
    __syncthreads();
  }

  // ---- epilogue part 1: router logits -> Lg; u1 -> gelu -> partial x ----
  float xp[4] = {0.f, 0.f, 0.f, 0.f};
#pragma unroll
  for (int n = 0; n < 20; ++n) {
    int col = c * 20 + n;
    if (col < NE) {
      float bias = br[col];
#pragma unroll
      for (int j = 0; j < 4; ++j) Lg[r * 4 + j][col] = acc[j][n] + bias;
    } else {
      int q = col - NE;
      float w2 = Wu2[q];
      float b1 = bu1[q];
#pragma unroll
      for (int j = 0; j < 4; ++j) {
        float h = acc[j][n] + b1;
        // exact GELU: 0.5*h*(1+erf(h/sqrt(2)))
        float g = 0.5f * h * (1.f + erff(h * 0.70710678118654752440f));
        xp[j] = fmaf(g, w2, xp[j]);
      }
    }
  }
#pragma unroll
  for (int j = 0; j < 4; ++j) Xp[c][r * 4 + j] = xp[j];
  __syncthreads();

  // deterministic fixed-order reduction of the 16 column-group partials
  if (tid < BM) {
    float x = bu2[0];
#pragma unroll
    for (int cc = 0; cc < 16; ++cc) x += Xp[cc][tid];
    Xs[tid] = x;
  }
  __syncthreads();

  // ---- epilogue part 2: per-token top-4 + masked softmax (1 wave/token) ----
  const int wave = tid >> 6;  // 0..3
  const int lane = tid & 63;
  const int Moff_i = 4 * M;       // start of indices section
  const int Moff_k = 8 * M;       // start of k section

  for (int t = wave; t < BM; t += 4) {
    float cur = Lg[t][lane];
    float topv[4];
    int topi[4];
#pragma unroll
    for (int s = 0; s < 4; ++s) {
      float mv = cur;
      int mi = lane;
#pragma unroll
      for (int off = 32; off >= 1; off >>= 1) {
        float ov = __shfl_xor(mv, off, 64);
        int oi = __shfl_xor(mi, off, 64);
        if (ov > mv || (ov == mv && oi < mi)) { mv = ov; mi = oi; }
      }
      topv[s] = mv;
      topi[s] = mi;
      if (lane == mi) cur = -INFINITY;  // remove winner; stable (low idx first)
    }
    if (lane == 0) {
      const int token = m0 + t;
      float x = Xs[t];
      float u = 1.f / (1.f + expf(-x));
      float kf = fmaf(3.f, u, 1.f);
      int kv = (int)rintf(kf);          // round-half-even, matches jnp.round
      kv = kv < 1 ? 1 : (kv > 4 ? 4 : kv);

      float w[4];
#pragma unroll
      for (int s = 0; s < 4; ++s) w[s] = (s < kv) ? topv[s] : 0.f;
      float mx = fmaxf(fmaxf(w[0], w[1]), fmaxf(w[2], w[3]));
      float e[4], sum = 0.f;
#pragma unroll
      for (int s = 0; s < 4; ++s) { e[s] = expf(w[s] - mx); sum += e[s]; }
      float inv = 1.f / sum;
#pragma unroll
      for (int s = 0; s < 4; ++s) {
        out[(size_t)token * 4 + s] = e[s] * inv;
        out[Moff_i + (size_t)token * 4 + s] = (s < kv) ? (float)topi[s] : -1.0f;
      }
      out[Moff_k + token] = (float)kv;
    }
  }
}

extern "C" void kernel_launch(void* const* d_in, const int* in_sizes, int n_in,
                              void* d_out, int out_size, void* d_ws, size_t ws_size,
                              hipStream_t stream) {
  (void)n_in; (void)d_ws; (void)ws_size; (void)out_size;
  const float* hs  = (const float*)d_in[0];
  const float* Wr  = (const float*)d_in[1];
  const float* br  = (const float*)d_in[2];
  const float* Wu1 = (const float*)d_in[3];
  const float* bu1 = (const float*)d_in[4];
  const float* Wu2 = (const float*)d_in[5];
  const float* bu2 = (const float*)d_in[6];
  float* out = (float*)d_out;

  const int M = in_sizes[0] / DIM;  // 32768 tokens
  dim3 grid(M / BM);                // 512 blocks
  dim3 block(256);
  hipLaunchKernelGGL(ur_fused, grid, block, 0, stream,
                     hs, Wr, br, Wu1, bu1, Wu2, bu2, out, M);
}